// Round 17
// baseline (4734.329 us; speedup 1.0000x reference)
//
#include <hip/hip_runtime.h>

// AttentionRNN: B=1024, T=256, U=256.
//  P[t] = x_t @ [Wemb|Wre|Wnew] (fp16 MFMA GEMM reading fp32 X directly, CT chunks).
//  Recurrent v9 (= v8, keep-alive pin moved to AGPR class): 256 blocks x 4 rows
//  x 8 waves. Weights persistent: kt0..5 in 192 regs/wave pinned with "+a"
//  (AGPR) keep-alive -- r16's "+v" pin forced per-step v_accvgpr shuttling and
//  arch-VGPR spill (WRITE 63MB); MFMA reads B from AGPR directly on gfx950's
//  unified file, so "+a" holds them resident with zero copies. kt6..7 in 128 KB
//  LDS. Phase 1 = two half-passes (acc[4], kt-outer, pipelined av). Phase 2
//  splits each row across a wave pair (2 cols/lane). 3 lgkm barriers/step.

typedef _Float16 f16;
typedef _Float16 f16x8 __attribute__((ext_vector_type(8)));
typedef _Float16 f16x4 __attribute__((ext_vector_type(4)));
typedef _Float16 f16x2 __attribute__((ext_vector_type(2)));
typedef float f32x4 __attribute__((ext_vector_type(4)));
typedef float f32x2 __attribute__((ext_vector_type(2)));

static __device__ __forceinline__ f32x4 mfma16(f16x8 a, f16x8 b, f32x4 c){
  return __builtin_amdgcn_mfma_f32_16x16x32_f16(a, b, c, 0, 0, 0);
}
static __device__ __forceinline__ float sigmoid_f(float x){
  return 1.0f / (1.0f + __expf(-x));
}
static __device__ __forceinline__ float tanh_f(float x){
  float e = __expf(2.0f * x);
  return 1.0f - 2.0f / (e + 1.0f);   // stable
}
static __device__ __forceinline__ void lgkm_barrier(){
  asm volatile("s_waitcnt lgkmcnt(0)" ::: "memory");
  __builtin_amdgcn_s_barrier();
}

// ------------- cast weights to fp16 -------------
// WcatT rows: [0,256) Wemb^T, [256,1024) Wre^T, [1024,1792) Wnew^T  (N x K row-major)
// WsrF fragment-packed [ct64][kt8][lane64][e8]: col=ct*16+(lane&15), k=kt*32+((lane>>4)&3)*8+e
__global__ void cast_w_kernel(const float* __restrict__ EK, const float* __restrict__ RE,
    const float* __restrict__ NW, const float* __restrict__ SK, const float* __restrict__ RS,
    f16* __restrict__ WcatT, f16* __restrict__ WsrF){
  int tid = blockIdx.x * 256 + threadIdx.x;
  if (tid < 458752){
    int n = tid >> 8, k = tid & 255;
    float v;
    if (n < 256)       v = EK[k*256 + n];
    else if (n < 1024) v = RE[k*768 + (n-256)];
    else               v = NW[k*768 + (n-1024)];
    WcatT[n*256 + k] = (f16)v;
  } else {
    int idx = tid - 458752;            // 0..262143
    int e    = idx & 7;
    int lane = (idx >> 3) & 63;
    int kt   = (idx >> 9) & 7;
    int ct   = idx >> 12;              // 0..63
    int col  = ct*16 + (lane & 15);
    int k    = kt*32 + ((lane >> 4) & 3)*8 + e;
    float v = (col < 256) ? SK[k*256 + col] : RS[k*768 + (col-256)];
    WsrF[idx] = (f16)v;
  }
}

// ---- GEMM: C[r=tsl*1024+b][0:1792) = X[b][t_start+tsl][:] @ WcatT^T (fp32 A in-reg cast) ----
__global__ __launch_bounds__(256, 2) void gemm_f16_kernel(
    const float* __restrict__ X, const f16* __restrict__ Bm,
    f16* __restrict__ C, int Mtiles, int t_start)
{
  __shared__ f16 As[128*64];
  __shared__ f16 Bs[128*64];
  const int NT = 14;
  const int nwg = Mtiles * NT;
  int bid = blockIdx.x, wg = bid;
  if ((nwg & 7) == 0){ int cpx = nwg >> 3; wg = (bid & 7) * cpx + (bid >> 3); }
  const int mt = wg / NT, nt = wg % NT;
  const int tsl = mt >> 3;
  const int b0  = (mt & 7) * 128;
  const int t   = t_start + tsl;
  const int n0  = nt * 128;
  const int tid = threadIdx.x;
  const int l = tid & 63, wid = tid >> 6;
  const int wr = wid >> 1, wc = wid & 1;
  const int srow = tid >> 3;
  const int scol = (tid & 7) * 8;

  const size_t ASTR = 32ull * 65536ull;   // 32 b-rows in fp32 elems (T*U = 65536)
  const float* Ab = X + ((size_t)(b0 + srow) * 256 + t) * 256 + scol;
  const f16*   Bb = Bm + ((size_t)(n0 + srow)) * 256 + scol;

  f16x8 ra[4], rb[4];
  #pragma unroll
  for (int j = 0; j < 4; ++j){
    f32x4 v0 = *(const f32x4*)(Ab + (size_t)j * ASTR);
    f32x4 v1 = *(const f32x4*)(Ab + (size_t)j * ASTR + 4);
    f16x8 h;
    #pragma unroll
    for (int jj = 0; jj < 8; ++jj) h[jj] = (f16)((jj < 4) ? v0[jj] : v1[jj-4]);
    ra[j] = h;
    rb[j] = *(const f16x8*)(Bb + (size_t)j * 32 * 256);
  }

  f32x4 acc[4][4];
  #pragma unroll
  for (int mi = 0; mi < 4; ++mi)
    #pragma unroll
    for (int ni = 0; ni < 4; ++ni)
      acc[mi][ni] = (f32x4){0.f,0.f,0.f,0.f};

  for (int kt = 0; kt < 4; ++kt){
    #pragma unroll
    for (int j = 0; j < 4; ++j){
      int row = srow + j*32;
      int e = (row*64 + scol) ^ ((row & 7) << 3);
      *(f16x8*)&As[e] = ra[j];
      *(f16x8*)&Bs[e] = rb[j];
    }
    __syncthreads();
    if (kt < 3){
      #pragma unroll
      for (int j = 0; j < 4; ++j){
        f32x4 v0 = *(const f32x4*)(Ab + (kt+1)*64 + (size_t)j * ASTR);
        f32x4 v1 = *(const f32x4*)(Ab + (kt+1)*64 + (size_t)j * ASTR + 4);
        f16x8 h;
        #pragma unroll
        for (int jj = 0; jj < 8; ++jj) h[jj] = (f16)((jj < 4) ? v0[jj] : v1[jj-4]);
        ra[j] = h;
        rb[j] = *(const f16x8*)(Bb + (kt+1)*64 + (size_t)j * 32 * 256);
      }
    }
    #pragma unroll
    for (int kk = 0; kk < 2; ++kk){
      f16x8 af[4], bfr[4];
      #pragma unroll
      for (int mi = 0; mi < 4; ++mi){
        int row = wr*64 + mi*16 + (l & 15);
        int e = (row*64 + kk*32 + (l >> 4)*8) ^ ((row & 7) << 3);
        af[mi] = *(const f16x8*)&As[e];
      }
      #pragma unroll
      for (int ni = 0; ni < 4; ++ni){
        int row = wc*64 + ni*16 + (l & 15);
        int e = (row*64 + kk*32 + (l >> 4)*8) ^ ((row & 7) << 3);
        bfr[ni] = *(const f16x8*)&Bs[e];
      }
      #pragma unroll
      for (int mi = 0; mi < 4; ++mi)
        #pragma unroll
        for (int ni = 0; ni < 4; ++ni)
          acc[mi][ni] = mfma16(af[mi], bfr[ni], acc[mi][ni]);
    }
    __syncthreads();
  }
  const size_t m0 = (size_t)mt * 128;
  #pragma unroll
  for (int mi = 0; mi < 4; ++mi){
    #pragma unroll
    for (int ni = 0; ni < 4; ++ni){
      int col = n0 + wc*64 + ni*16 + (l & 15);
      size_t row = m0 + wr*64 + mi*16 + ((l >> 4) * 4);
      #pragma unroll
      for (int j = 0; j < 4; ++j)
        C[(row + j) * 1792 + col] = (f16)acc[mi][ni][j];
    }
  }
}

// ---------- recurrent v9: 256 blocks x 4 rows, 512 threads (8 waves) ----------
__global__ __launch_bounds__(512, 1) void recurrent_kernel(
    const f16* __restrict__ P, const f16* __restrict__ WsrF,
    const float* __restrict__ bias, const float* __restrict__ Lk,
    float* __restrict__ state, float* __restrict__ out,
    int t0, int nsteps)
{
  __shared__ f16 Wl[8*8192];             // weights kt6..7: 128 KB
  __shared__ f16 qg16[4*1032];           // qg as f16: [row j][1032]
  __shared__ f16 stA[8*520];             // state f16, fragment-major [kt][lane][8]
  __shared__ __align__(16) float sb[256];
  __shared__ __align__(16) float sl[256];
  __shared__ float sp[4][2][3];          // score partials [row][half][slot]

  const int tid = threadIdx.x;
  const int l = tid & 63, w = tid >> 6;  // 8 waves
  const int r0 = blockIdx.x * 4;
  const int arow = l & 15, agrp = l >> 4;
  const int r = w >> 1, h = w & 1;       // row 0..3, half 0..1 (wave pair per row)
  const int c2 = h*128 + l*2;            // 2 cols/lane
  const int gb = r0 + r;
  const size_t SL = 1024ull*1792ull;
  const size_t gbo = (size_t)gb*1792;

  if (tid < 256){ sb[tid] = bias[tid]; sl[tid] = Lk[tid]; }
  for (int j = tid; j < 8*520; j += 512) stA[j] = (f16)0.f;

  // ---- persistent weights: kt0..5 -> 192 regs/wave (AGPR-resident) ----
  const f16* const wbase = WsrF + (size_t)w*32768 + l*8;   // wave's 8 ct-tiles
  f16x8 Wreg[8][6];
  #pragma unroll
  for (int ct = 0; ct < 8; ++ct)
    #pragma unroll
    for (int kt = 0; kt < 6; ++kt)
      Wreg[ct][kt] = *(const f16x8*)(wbase + (ct*8 + kt)*512);
  // ---- kt6..7 -> LDS (128 KB, loaded once) ----
  #pragma unroll
  for (int ct = 0; ct < 8; ++ct)
    #pragma unroll
    for (int k2 = 0; k2 < 2; ++k2)
      *(f16x8*)&Wl[w*8192 + (ct*2 + k2)*512 + l*8] =
          *(const f16x8*)(wbase + (ct*8 + 6 + k2)*512);
  __syncthreads();

  // state: 2 cols/lane, rows 0..3 of stA valid (rest stay zero)
  f32x2 sn = *(const f32x2*)(state + (size_t)gb*256 + c2);
  const int kt0 = c2 >> 5, g0 = (c2 >> 3) & 3, e0 = c2 & 7;
  f16* const sa = &stA[kt0*520 + (g0*16 + r)*8 + e0];
  { f16x2 hh; hh[0]=(f16)sn[0]; hh[1]=(f16)sn[1]; *(f16x2*)sa = hh; }
  lgkm_barrier();

  for (int i = 0; i < nsteps; ++i){
    const int t = t0 + i;
    const f16* p2 = P + (size_t)(i+2)*SL + gbo;
    const f16* p1 = P + (size_t)(i+1)*SL + gbo;
    const f16* p0 = P + (size_t)(i+0)*SL + gbo;

    // ---- keep-alive in the AGPR class: holds weights resident with ZERO
    //      copies (MFMA reads B from AGPR on gfx950 unified file). r16's "+v"
    //      pin forced v_accvgpr shuttling + arch-VGPR spill. ----
    #pragma unroll
    for (int ct = 0; ct < 8; ++ct)
      #pragma unroll
      for (int kt = 0; kt < 6; ++kt)
        asm volatile("" : "+a"(Wreg[ct][kt]));

    // ---- scores-critical loads only, upfront (3 regs; GRU loads deferred) ----
    const f16x2 cE2 = *(const f16x2*)(p2 + c2);
    const f16x2 E0  = *(const f16x2*)(p0 + c2);
    const f16x2 E1  = *(const f16x2*)(p1 + c2);

    // ---- phase 1: two half-passes (acc[4], kt-outer, pipelined av) ----
    #pragma unroll
    for (int half = 0; half < 2; ++half){
      f32x4 acc[4];
      #pragma unroll
      for (int c = 0; c < 4; ++c) acc[c] = (f32x4){0.f,0.f,0.f,0.f};
      f16x8 av0 = *(const f16x8*)&stA[0*520 + l*8];
      f16x8 av1 = *(const f16x8*)&stA[1*520 + l*8];
      #pragma unroll
      for (int kt = 0; kt < 8; ++kt){
        const f16x8 avc = (kt & 1) ? av1 : av0;
        if (kt < 6){
          f16x8 nx = *(const f16x8*)&stA[(kt+2)*520 + l*8];
          if (kt & 1) av1 = nx; else av0 = nx;
        }
        #pragma unroll
        for (int c = 0; c < 4; ++c){
          const int ct = half*4 + c;
          f16x8 B = (kt < 6) ? Wreg[ct][kt]
                             : *(const f16x8*)&Wl[w*8192 + (ct*2 + (kt-6))*512 + l*8];
          acc[c] = mfma16(avc, B, acc[c]);
        }
      }
      // qg write: keep C rows 0..3 only (agrp==0); col = w*128 + ct*16 + arow
      if (agrp == 0){
        #pragma unroll
        for (int c = 0; c < 4; ++c){
          const int ct = half*4 + c;
          #pragma unroll
          for (int j = 0; j < 4; ++j)
            qg16[j*1032 + w*128 + ct*16 + arow] = (f16)acc[c][j];
        }
      }
    }

    // ---- deferred cold/warm GRU loads (consumed ~1.5K cycles away) ----
    const f16x2 cU  = *(const f16x2*)(p2 +  256 + c2);
    const f16x2 cR  = *(const f16x2*)(p2 +  512 + c2);
    const f16x2 cC  = *(const f16x2*)(p2 +  768 + c2);
    const f16x2 cNU = *(const f16x2*)(p2 + 1024 + c2);
    const f16x2 cNR = *(const f16x2*)(p2 + 1280 + c2);
    const f16x2 cNC = *(const f16x2*)(p2 + 1536 + c2);
    lgkm_barrier();

    const f16x2 U1 = *(const f16x2*)(p1 + 256 + c2);
    const f16x2 R1 = *(const f16x2*)(p1 + 512 + c2);
    const f16x2 C1 = *(const f16x2*)(p1 + 768 + c2);
    const f16x2 U2 = *(const f16x2*)(p0 + 256 + c2);
    const f16x2 R2 = *(const f16x2*)(p0 + 512 + c2);
    const f16x2 C2 = *(const f16x2*)(p0 + 768 + c2);

    // ---- phase 2a: score partials (row r, 128 cols per wave, 2/lane) ----
    {
      const f16x2 qv = *(const f16x2*)&qg16[r*1032 + c2];
      const f32x2 bb = *(const f32x2*)&sb[c2];
      const f32x2 lk = *(const f32x2*)&sl[c2];
      float s0 = 0.f, s1 = 0.f, s2 = 0.f;
      #pragma unroll
      for (int j = 0; j < 2; ++j){
        const float qb = (float)qv[j] + bb[j];
        s0 += tanh_f((float)E0[j]  + qb) * lk[j];
        s1 += tanh_f((float)E1[j]  + qb) * lk[j];
        s2 += tanh_f((float)cE2[j] + qb) * lk[j];
      }
      #pragma unroll
      for (int off = 32; off; off >>= 1){
        s0 += __shfl_xor(s0, off);
        s1 += __shfl_xor(s1, off);
        s2 += __shfl_xor(s2, off);
      }
      if (l == 0){ sp[r][h][0] = s0; sp[r][h][1] = s1; sp[r][h][2] = s2; }
    }
    lgkm_barrier();

    // ---- phase 2b: softmax (from partials, redundant per lane) + GRU ----
    {
      const float s0 = sp[r][0][0] + sp[r][1][0];
      const float s1 = sp[r][0][1] + sp[r][1][1];
      const float s2 = sp[r][0][2] + sp[r][1][2];
      const float mx = fmaxf(fmaxf(s0, s1), s2);
      const float x0 = __expf(s0 - mx), x1 = __expf(s1 - mx), x2 = __expf(s2 - mx);
      const float inv = 1.0f / (x0 + x1 + x2);
      const float pr0 = x0*inv, pr1 = x1*inv, pr2 = x2*inv;

      const f16x2 qu = *(const f16x2*)&qg16[r*1032 + 256 + c2];
      const f16x2 qr = *(const f16x2*)&qg16[r*1032 + 512 + c2];
      const f16x2 qc = *(const f16x2*)&qg16[r*1032 + 768 + c2];
      #pragma unroll
      for (int j = 0; j < 2; ++j){
        const float geu = pr2*(float)cU[j] + pr1*(float)U1[j] + pr0*(float)U2[j];
        const float ger = pr2*(float)cR[j] + pr1*(float)R1[j] + pr0*(float)R2[j];
        const float gec = pr2*(float)cC[j] + pr1*(float)C1[j] + pr0*(float)C2[j];
        const float up   = sigmoid_f((float)qu[j] + geu + (float)cNU[j]);
        const float rp   = sigmoid_f((float)qr[j] + ger + (float)cNR[j]);
        const float cand = tanh_f(rp*(float)qc[j] + gec + (float)cNC[j]);
        sn[j] = (1.0f - up)*sn[j] + up*cand;
      }
      { f16x2 hh; hh[0]=(f16)sn[0]; hh[1]=(f16)sn[1]; *(f16x2*)sa = hh; }
      if (t == 255) *(f32x2*)(out + (size_t)gb*256 + c2) = sn;
    }
    lgkm_barrier();
  }

  *(f32x2*)(state + (size_t)gb*256 + c2) = sn;
}

// ---------------------------------- launch ----------------------------------
extern "C" void kernel_launch(void* const* d_in, const int* in_sizes, int n_in,
                              void* d_out, int out_size, void* d_ws, size_t ws_size,
                              hipStream_t stream)
{
  const float* X  = (const float*)d_in[0];
  const float* EK = (const float*)d_in[1];
  const float* SK = (const float*)d_in[2];
  const float* BI = (const float*)d_in[3];
  const float* LK = (const float*)d_in[4];
  const float* RS = (const float*)d_in[5];
  const float* RE = (const float*)d_in[6];
  const float* NW = (const float*)d_in[7];
  float* out = (float*)d_out;
  char* ws = (char*)d_ws;

  const size_t slabB = 1024ull * 1792ull * 2ull;   // 3,670,016 B
  const size_t wB    = 917504ull + 524288ull + 1048576ull;
  int CT = 4;
  if      (ws_size >= 66ull*slabB + wB) CT = 64;
  else if (ws_size >= 34ull*slabB + wB) CT = 32;
  else if (ws_size >= 18ull*slabB + wB) CT = 16;
  else if (ws_size >= 10ull*slabB + wB) CT = 8;

  f16* P = (f16*)ws;
  size_t poff = (size_t)(CT + 2) * slabB;
  f16* WcatT = (f16*)(ws + poff);
  f16* WsrF  = (f16*)(ws + poff + 917504ull);
  float* state = (float*)(ws + poff + 917504ull + 524288ull);

  hipMemsetAsync(state, 0, 1048576ull, stream);
  hipMemsetAsync(P, 0, 2ull*slabB, stream);        // zero "virtual" slabs t=-2,-1
  cast_w_kernel<<<2816, 256, 0, stream>>>(EK, RE, NW, SK, RS, WcatT, WsrF);

  const int nch = 256 / CT;
  for (int c = 0; c < nch; ++c){
    const int t0 = c * CT;
    const int t_start  = (c == 0) ? 0 : (t0 - 2);
    const int slab_off = (c == 0) ? 2 : 0;
    const int Mtiles = (((c == 0) ? CT : (CT + 2)) * 1024) / 128;
    gemm_f16_kernel<<<Mtiles * 14, 256, 0, stream>>>(
        X, WcatT, P + (size_t)slab_off * 1024 * 1792, Mtiles, t_start);
    recurrent_kernel<<<256, 512, 0, stream>>>(P, WsrF, BI, LK, state, out, t0, CT);
  }
}

// Round 18
// 1645.720 us; speedup vs baseline: 2.8768x; 2.8768x over previous
//
#include <hip/hip_runtime.h>

// AttentionRNN: B=1024, T=256, U=256.
//  P[t] = x_t @ [Wemb|Wre|Wnew] (fp16 MFMA GEMM reading fp32 X directly, CT chunks).
//  Recurrent v10 (reduced sustained pin): 256 blocks x 4 rows x 8 waves.
//  Register model: 512-thread block => 2 waves/SIMD => HARD 256-reg/wave cap.
//  r16's 192-reg sustained pin + ~55 transient left no slack -> 63MB/dispatch
//  scratch spill (~100us). Now: kt0..3 pinned (128 regs, "+v"); kt4..5 STREAMED
//  from L2 each step (issued before P loads so vmcnt ordering never stalls the
//  pass on HBM); kt6..7 in 128 KB LDS. Phase 2 splits each row across a wave
//  pair (2 cols/lane), partials via LDS. 3 lgkm-only barriers/step.

typedef _Float16 f16;
typedef _Float16 f16x8 __attribute__((ext_vector_type(8)));
typedef _Float16 f16x4 __attribute__((ext_vector_type(4)));
typedef _Float16 f16x2 __attribute__((ext_vector_type(2)));
typedef float f32x4 __attribute__((ext_vector_type(4)));
typedef float f32x2 __attribute__((ext_vector_type(2)));

static __device__ __forceinline__ f32x4 mfma16(f16x8 a, f16x8 b, f32x4 c){
  return __builtin_amdgcn_mfma_f32_16x16x32_f16(a, b, c, 0, 0, 0);
}
static __device__ __forceinline__ float sigmoid_f(float x){
  return 1.0f / (1.0f + __expf(-x));
}
static __device__ __forceinline__ float tanh_f(float x){
  float e = __expf(2.0f * x);
  return 1.0f - 2.0f / (e + 1.0f);   // stable
}
static __device__ __forceinline__ void lgkm_barrier(){
  asm volatile("s_waitcnt lgkmcnt(0)" ::: "memory");
  __builtin_amdgcn_s_barrier();
}

// ------------- cast weights to fp16 -------------
// WcatT rows: [0,256) Wemb^T, [256,1024) Wre^T, [1024,1792) Wnew^T  (N x K row-major)
// WsrF fragment-packed [ct64][kt8][lane64][e8]: col=ct*16+(lane&15), k=kt*32+((lane>>4)&3)*8+e
__global__ void cast_w_kernel(const float* __restrict__ EK, const float* __restrict__ RE,
    const float* __restrict__ NW, const float* __restrict__ SK, const float* __restrict__ RS,
    f16* __restrict__ WcatT, f16* __restrict__ WsrF){
  int tid = blockIdx.x * 256 + threadIdx.x;
  if (tid < 458752){
    int n = tid >> 8, k = tid & 255;
    float v;
    if (n < 256)       v = EK[k*256 + n];
    else if (n < 1024) v = RE[k*768 + (n-256)];
    else               v = NW[k*768 + (n-1024)];
    WcatT[n*256 + k] = (f16)v;
  } else {
    int idx = tid - 458752;            // 0..262143
    int e    = idx & 7;
    int lane = (idx >> 3) & 63;
    int kt   = (idx >> 9) & 7;
    int ct   = idx >> 12;              // 0..63
    int col  = ct*16 + (lane & 15);
    int k    = kt*32 + ((lane >> 4) & 3)*8 + e;
    float v = (col < 256) ? SK[k*256 + col] : RS[k*768 + (col-256)];
    WsrF[idx] = (f16)v;
  }
}

// ---- GEMM: C[r=tsl*1024+b][0:1792) = X[b][t_start+tsl][:] @ WcatT^T (fp32 A in-reg cast) ----
__global__ __launch_bounds__(256, 2) void gemm_f16_kernel(
    const float* __restrict__ X, const f16* __restrict__ Bm,
    f16* __restrict__ C, int Mtiles, int t_start)
{
  __shared__ f16 As[128*64];
  __shared__ f16 Bs[128*64];
  const int NT = 14;
  const int nwg = Mtiles * NT;
  int bid = blockIdx.x, wg = bid;
  if ((nwg & 7) == 0){ int cpx = nwg >> 3; wg = (bid & 7) * cpx + (bid >> 3); }
  const int mt = wg / NT, nt = wg % NT;
  const int tsl = mt >> 3;
  const int b0  = (mt & 7) * 128;
  const int t   = t_start + tsl;
  const int n0  = nt * 128;
  const int tid = threadIdx.x;
  const int l = tid & 63, wid = tid >> 6;
  const int wr = wid >> 1, wc = wid & 1;
  const int srow = tid >> 3;
  const int scol = (tid & 7) * 8;

  const size_t ASTR = 32ull * 65536ull;   // 32 b-rows in fp32 elems (T*U = 65536)
  const float* Ab = X + ((size_t)(b0 + srow) * 256 + t) * 256 + scol;
  const f16*   Bb = Bm + ((size_t)(n0 + srow)) * 256 + scol;

  f16x8 ra[4], rb[4];
  #pragma unroll
  for (int j = 0; j < 4; ++j){
    f32x4 v0 = *(const f32x4*)(Ab + (size_t)j * ASTR);
    f32x4 v1 = *(const f32x4*)(Ab + (size_t)j * ASTR + 4);
    f16x8 h;
    #pragma unroll
    for (int jj = 0; jj < 8; ++jj) h[jj] = (f16)((jj < 4) ? v0[jj] : v1[jj-4]);
    ra[j] = h;
    rb[j] = *(const f16x8*)(Bb + (size_t)j * 32 * 256);
  }

  f32x4 acc[4][4];
  #pragma unroll
  for (int mi = 0; mi < 4; ++mi)
    #pragma unroll
    for (int ni = 0; ni < 4; ++ni)
      acc[mi][ni] = (f32x4){0.f,0.f,0.f,0.f};

  for (int kt = 0; kt < 4; ++kt){
    #pragma unroll
    for (int j = 0; j < 4; ++j){
      int row = srow + j*32;
      int e = (row*64 + scol) ^ ((row & 7) << 3);
      *(f16x8*)&As[e] = ra[j];
      *(f16x8*)&Bs[e] = rb[j];
    }
    __syncthreads();
    if (kt < 3){
      #pragma unroll
      for (int j = 0; j < 4; ++j){
        f32x4 v0 = *(const f32x4*)(Ab + (kt+1)*64 + (size_t)j * ASTR);
        f32x4 v1 = *(const f32x4*)(Ab + (kt+1)*64 + (size_t)j * ASTR + 4);
        f16x8 h;
        #pragma unroll
        for (int jj = 0; jj < 8; ++jj) h[jj] = (f16)((jj < 4) ? v0[jj] : v1[jj-4]);
        ra[j] = h;
        rb[j] = *(const f16x8*)(Bb + (kt+1)*64 + (size_t)j * 32 * 256);
      }
    }
    #pragma unroll
    for (int kk = 0; kk < 2; ++kk){
      f16x8 af[4], bfr[4];
      #pragma unroll
      for (int mi = 0; mi < 4; ++mi){
        int row = wr*64 + mi*16 + (l & 15);
        int e = (row*64 + kk*32 + (l >> 4)*8) ^ ((row & 7) << 3);
        af[mi] = *(const f16x8*)&As[e];
      }
      #pragma unroll
      for (int ni = 0; ni < 4; ++ni){
        int row = wc*64 + ni*16 + (l & 15);
        int e = (row*64 + kk*32 + (l >> 4)*8) ^ ((row & 7) << 3);
        bfr[ni] = *(const f16x8*)&Bs[e];
      }
      #pragma unroll
      for (int mi = 0; mi < 4; ++mi)
        #pragma unroll
        for (int ni = 0; ni < 4; ++ni)
          acc[mi][ni] = mfma16(af[mi], bfr[ni], acc[mi][ni]);
    }
    __syncthreads();
  }
  const size_t m0 = (size_t)mt * 128;
  #pragma unroll
  for (int mi = 0; mi < 4; ++mi){
    #pragma unroll
    for (int ni = 0; ni < 4; ++ni){
      int col = n0 + wc*64 + ni*16 + (l & 15);
      size_t row = m0 + wr*64 + mi*16 + ((l >> 4) * 4);
      #pragma unroll
      for (int j = 0; j < 4; ++j)
        C[(row + j) * 1792 + col] = (f16)acc[mi][ni][j];
    }
  }
}

// ---------- recurrent v10: 256 blocks x 4 rows, 512 threads (8 waves) ----------
__global__ __launch_bounds__(512, 1) void recurrent_kernel(
    const f16* __restrict__ P, const f16* __restrict__ WsrF,
    const float* __restrict__ bias, const float* __restrict__ Lk,
    float* __restrict__ state, float* __restrict__ out,
    int t0, int nsteps)
{
  __shared__ f16 Wl[8*8192];             // weights kt6..7: 128 KB
  __shared__ f16 qg16[4*1032];           // qg as f16: [row j][1032]
  __shared__ f16 stA[8*520];             // state f16, fragment-major [kt][lane][8]
  __shared__ __align__(16) float sb[256];
  __shared__ __align__(16) float sl[256];
  __shared__ float sp[4][2][3];          // score partials [row][half][slot]

  const int tid = threadIdx.x;
  const int l = tid & 63, w = tid >> 6;  // 8 waves
  const int r0 = blockIdx.x * 4;
  const int arow = l & 15, agrp = l >> 4;
  const int r = w >> 1, h = w & 1;       // row 0..3, half 0..1 (wave pair per row)
  const int c2 = h*128 + l*2;            // 2 cols/lane
  const int gb = r0 + r;
  const size_t SL = 1024ull*1792ull;
  const size_t gbo = (size_t)gb*1792;

  if (tid < 256){ sb[tid] = bias[tid]; sl[tid] = Lk[tid]; }
  for (int j = tid; j < 8*520; j += 512) stA[j] = (f16)0.f;

  // ---- persistent weights: kt0..3 -> 128 regs/wave (sustained pin) ----
  const f16* const wbase = WsrF + (size_t)w*32768 + l*8;   // wave's 8 ct-tiles
  f16x8 Wreg[8][4];
  #pragma unroll
  for (int ct = 0; ct < 8; ++ct)
    #pragma unroll
    for (int kt = 0; kt < 4; ++kt)
      Wreg[ct][kt] = *(const f16x8*)(wbase + (ct*8 + kt)*512);
  // ---- kt6..7 -> LDS (128 KB, loaded once) ----
  #pragma unroll
  for (int ct = 0; ct < 8; ++ct)
    #pragma unroll
    for (int k2 = 0; k2 < 2; ++k2)
      *(f16x8*)&Wl[w*8192 + (ct*2 + k2)*512 + l*8] =
          *(const f16x8*)(wbase + (ct*8 + 6 + k2)*512);
  __syncthreads();

  // state: 2 cols/lane, rows 0..3 of stA valid (rest stay zero)
  f32x2 sn = *(const f32x2*)(state + (size_t)gb*256 + c2);
  const int kt0 = c2 >> 5, g0 = (c2 >> 3) & 3, e0 = c2 & 7;
  f16* const sa = &stA[kt0*520 + (g0*16 + r)*8 + e0];
  { f16x2 hh; hh[0]=(f16)sn[0]; hh[1]=(f16)sn[1]; *(f16x2*)sa = hh; }
  lgkm_barrier();

  for (int i = 0; i < nsteps; ++i){
    const int t = t0 + i;
    const f16* p2 = P + (size_t)(i+2)*SL + gbo;
    const f16* p1 = P + (size_t)(i+1)*SL + gbo;
    const f16* p0 = P + (size_t)(i+0)*SL + gbo;

    // ---- keep-alive: pin the SUSTAINED weight set (kt0..3 = 128 regs) ----
    #pragma unroll
    for (int ct = 0; ct < 8; ++ct)
      #pragma unroll
      for (int kt = 0; kt < 4; ++kt)
        asm volatile("" : "+v"(Wreg[ct][kt]));

    // ---- stream kt4..5 from L2 (transient 64 regs; issued FIRST so the
    //      pass's waits never drain the HBM P loads issued below) ----
    f16x8 S4[8], S5[8];
    #pragma unroll
    for (int ct = 0; ct < 8; ++ct) S4[ct] = *(const f16x8*)(wbase + (ct*8 + 4)*512);
    #pragma unroll
    for (int ct = 0; ct < 8; ++ct) S5[ct] = *(const f16x8*)(wbase + (ct*8 + 5)*512);

    // ---- scores-critical P loads (GRU loads deferred past the pass) ----
    const f16x2 cE2 = *(const f16x2*)(p2 + c2);
    const f16x2 E0  = *(const f16x2*)(p0 + c2);
    const f16x2 E1  = *(const f16x2*)(p1 + c2);

    // ---- phase 1: two half-passes (acc[4], kt-outer, pipelined av) ----
    #pragma unroll
    for (int half = 0; half < 2; ++half){
      f32x4 acc[4];
      #pragma unroll
      for (int c = 0; c < 4; ++c) acc[c] = (f32x4){0.f,0.f,0.f,0.f};
      f16x8 av0 = *(const f16x8*)&stA[0*520 + l*8];
      f16x8 av1 = *(const f16x8*)&stA[1*520 + l*8];
      #pragma unroll
      for (int kt = 0; kt < 8; ++kt){
        const f16x8 avc = (kt & 1) ? av1 : av0;
        if (kt < 6){
          f16x8 nx = *(const f16x8*)&stA[(kt+2)*520 + l*8];
          if (kt & 1) av1 = nx; else av0 = nx;
        }
        #pragma unroll
        for (int c = 0; c < 4; ++c){
          const int ct = half*4 + c;
          f16x8 B;
          if      (kt < 4)  B = Wreg[ct][kt];
          else if (kt == 4) B = S4[ct];
          else if (kt == 5) B = S5[ct];
          else              B = *(const f16x8*)&Wl[w*8192 + (ct*2 + (kt-6))*512 + l*8];
          acc[c] = mfma16(avc, B, acc[c]);
        }
      }
      // qg write: keep C rows 0..3 only (agrp==0); col = w*128 + ct*16 + arow
      if (agrp == 0){
        #pragma unroll
        for (int c = 0; c < 4; ++c){
          const int ct = half*4 + c;
          #pragma unroll
          for (int j = 0; j < 4; ++j)
            qg16[j*1032 + w*128 + ct*16 + arow] = (f16)acc[c][j];
        }
      }
    }

    // ---- deferred cold/warm GRU loads (consumed ~1.5K cycles away) ----
    const f16x2 cU  = *(const f16x2*)(p2 +  256 + c2);
    const f16x2 cR  = *(const f16x2*)(p2 +  512 + c2);
    const f16x2 cC  = *(const f16x2*)(p2 +  768 + c2);
    const f16x2 cNU = *(const f16x2*)(p2 + 1024 + c2);
    const f16x2 cNR = *(const f16x2*)(p2 + 1280 + c2);
    const f16x2 cNC = *(const f16x2*)(p2 + 1536 + c2);
    lgkm_barrier();

    const f16x2 U1 = *(const f16x2*)(p1 + 256 + c2);
    const f16x2 R1 = *(const f16x2*)(p1 + 512 + c2);
    const f16x2 C1 = *(const f16x2*)(p1 + 768 + c2);
    const f16x2 U2 = *(const f16x2*)(p0 + 256 + c2);
    const f16x2 R2 = *(const f16x2*)(p0 + 512 + c2);
    const f16x2 C2 = *(const f16x2*)(p0 + 768 + c2);

    // ---- phase 2a: score partials (row r, 128 cols per wave, 2/lane) ----
    {
      const f16x2 qv = *(const f16x2*)&qg16[r*1032 + c2];
      const f32x2 bb = *(const f32x2*)&sb[c2];
      const f32x2 lk = *(const f32x2*)&sl[c2];
      float s0 = 0.f, s1 = 0.f, s2 = 0.f;
      #pragma unroll
      for (int j = 0; j < 2; ++j){
        const float qb = (float)qv[j] + bb[j];
        s0 += tanh_f((float)E0[j]  + qb) * lk[j];
        s1 += tanh_f((float)E1[j]  + qb) * lk[j];
        s2 += tanh_f((float)cE2[j] + qb) * lk[j];
      }
      #pragma unroll
      for (int off = 32; off; off >>= 1){
        s0 += __shfl_xor(s0, off);
        s1 += __shfl_xor(s1, off);
        s2 += __shfl_xor(s2, off);
      }
      if (l == 0){ sp[r][h][0] = s0; sp[r][h][1] = s1; sp[r][h][2] = s2; }
    }
    lgkm_barrier();

    // ---- phase 2b: softmax (from partials, redundant per lane) + GRU ----
    {
      const float s0 = sp[r][0][0] + sp[r][1][0];
      const float s1 = sp[r][0][1] + sp[r][1][1];
      const float s2 = sp[r][0][2] + sp[r][1][2];
      const float mx = fmaxf(fmaxf(s0, s1), s2);
      const float x0 = __expf(s0 - mx), x1 = __expf(s1 - mx), x2 = __expf(s2 - mx);
      const float inv = 1.0f / (x0 + x1 + x2);
      const float pr0 = x0*inv, pr1 = x1*inv, pr2 = x2*inv;

      const f16x2 qu = *(const f16x2*)&qg16[r*1032 + 256 + c2];
      const f16x2 qr = *(const f16x2*)&qg16[r*1032 + 512 + c2];
      const f16x2 qc = *(const f16x2*)&qg16[r*1032 + 768 + c2];
      #pragma unroll
      for (int j = 0; j < 2; ++j){
        const float geu = pr2*(float)cU[j] + pr1*(float)U1[j] + pr0*(float)U2[j];
        const float ger = pr2*(float)cR[j] + pr1*(float)R1[j] + pr0*(float)R2[j];
        const float gec = pr2*(float)cC[j] + pr1*(float)C1[j] + pr0*(float)C2[j];
        const float up   = sigmoid_f((float)qu[j] + geu + (float)cNU[j]);
        const float rp   = sigmoid_f((float)qr[j] + ger + (float)cNR[j]);
        const float cand = tanh_f(rp*(float)qc[j] + gec + (float)cNC[j]);
        sn[j] = (1.0f - up)*sn[j] + up*cand;
      }
      { f16x2 hh; hh[0]=(f16)sn[0]; hh[1]=(f16)sn[1]; *(f16x2*)sa = hh; }
      if (t == 255) *(f32x2*)(out + (size_t)gb*256 + c2) = sn;
    }
    lgkm_barrier();
  }

  *(f32x2*)(state + (size_t)gb*256 + c2) = sn;
}

// ---------------------------------- launch ----------------------------------
extern "C" void kernel_launch(void* const* d_in, const int* in_sizes, int n_in,
                              void* d_out, int out_size, void* d_ws, size_t ws_size,
                              hipStream_t stream)
{
  const float* X  = (const float*)d_in[0];
  const float* EK = (const float*)d_in[1];
  const float* SK = (const float*)d_in[2];
  const float* BI = (const float*)d_in[3];
  const float* LK = (const float*)d_in[4];
  const float* RS = (const float*)d_in[5];
  const float* RE = (const float*)d_in[6];
  const float* NW = (const float*)d_in[7];
  float* out = (float*)d_out;
  char* ws = (char*)d_ws;

  const size_t slabB = 1024ull * 1792ull * 2ull;   // 3,670,016 B
  const size_t wB    = 917504ull + 524288ull + 1048576ull;
  int CT = 4;
  if      (ws_size >= 66ull*slabB + wB) CT = 64;
  else if (ws_size >= 34ull*slabB + wB) CT = 32;
  else if (ws_size >= 18ull*slabB + wB) CT = 16;
  else if (ws_size >= 10ull*slabB + wB) CT = 8;

  f16* P = (f16*)ws;
  size_t poff = (size_t)(CT + 2) * slabB;
  f16* WcatT = (f16*)(ws + poff);
  f16* WsrF  = (f16*)(ws + poff + 917504ull);
  float* state = (float*)(ws + poff + 917504ull + 524288ull);

  hipMemsetAsync(state, 0, 1048576ull, stream);
  hipMemsetAsync(P, 0, 2ull*slabB, stream);        // zero "virtual" slabs t=-2,-1
  cast_w_kernel<<<2816, 256, 0, stream>>>(EK, RE, NW, SK, RS, WcatT, WsrF);

  const int nch = 256 / CT;
  for (int c = 0; c < nch; ++c){
    const int t0 = c * CT;
    const int t_start  = (c == 0) ? 0 : (t0 - 2);
    const int slab_off = (c == 0) ? 2 : 0;
    const int Mtiles = (((c == 0) ? CT : (CT + 2)) * 1024) / 128;
    gemm_f16_kernel<<<Mtiles * 14, 256, 0, stream>>>(
        X, WcatT, P + (size_t)slab_off * 1024 * 1792, Mtiles, t_start);
    recurrent_kernel<<<256, 512, 0, stream>>>(P, WsrF, BI, LK, state, out, t0, CT);
  }
}